// Round 13
// baseline (247.236 us; speedup 1.0000x reference)
//
#include <hip/hip_runtime.h>
#include <hip/hip_fp16.h>
#include <hip/hip_cooperative_groups.h>

namespace cg = cooperative_groups;

#define F1 64
#define F2 32
#define FIN 13
#define BSH 9                 // bucket = dst >> 9  (512 nodes/bucket)
#define BNODES 512
#define TILE 4096             // edges per scatter tile
#define CAP 8192              // LDS sort capacity (bucket mean 6400, sd ~80)
#define SRCMASK 0x7FFFFF      // 23-bit src (N < 8.4M)
#define PB 256                // prep blocks
#define BPAD 208              // bpart row stride (>= NBK)

// ============ fused preprocessing: hist -> scan -> scatter -> per-bucket sort ============
__global__ void __launch_bounds__(1024)
k_prep(const int* __restrict__ src, const int* __restrict__ dst,
       const float* __restrict__ x, int* __restrict__ bpart,
       int* __restrict__ bbase, int* __restrict__ gcur,
       int* __restrict__ rowstart, float* __restrict__ dinv,
       int* __restrict__ csr, unsigned* __restrict__ pairs,
       __half2* __restrict__ xnh, int N, int E, int NBK) {
    cg::grid_group grid = cg::this_grid();
    __shared__ int lh[256];
    __shared__ int lbase[256];
    __shared__ int s[256];
    __shared__ int cnt[BNODES];
    __shared__ int lex[BNODES];
    __shared__ int lcur[BNODES];
    __shared__ float dinvl[BNODES];
    __shared__ int lsorted[CAP];
    int tid = threadIdx.x;
    int bid = blockIdx.x;
    const int NB = gridDim.x;     // PB

    // ---- phase 1: per-block bucket histogram partials (no pre-zero needed) ----
    for (int i = tid; i < NBK; i += 1024) lh[i] = 0;
    __syncthreads();
    for (long e = (long)bid * 1024 + tid; e < E; e += (long)NB * 1024)
        atomicAdd(&lh[dst[e] >> BSH], 1);
    __syncthreads();
    for (int i = tid; i < NBK; i += 1024) bpart[bid * BPAD + i] = lh[i];
    grid.sync();

    // ---- phase 2: block 0 reduces partials + exclusive scan -> bbase, gcur ----
    if (bid == 0) {
        int v = 0;
        if (tid < 256) {
            if (tid < NBK)
                for (int k = 0; k < NB; ++k) v += bpart[k * BPAD + tid];
            s[tid] = v;
        }
        __syncthreads();
        for (int off = 1; off < 256; off <<= 1) {
            int a = 0;
            if (tid < 256 && tid >= off) a = s[tid - off];
            __syncthreads();
            if (tid < 256) s[tid] += a;
            __syncthreads();
        }
        if (tid < NBK) {
            int excl = s[tid] - v;
            bbase[tid] = excl;
            gcur[tid] = excl;
            if (tid == NBK - 1) bbase[NBK] = s[tid];
        }
        if (tid == 0) rowstart[N] = E;
    }
    grid.sync();

    // ---- phase 3: partition edges into bucket-contiguous packed pairs ----
    int ntiles = (E + TILE - 1) / TILE;
    for (int t = bid; t < ntiles; t += NB) {
        long t0 = (long)t * TILE;
        int lim = ((long)E - t0 < (long)TILE) ? (int)((long)E - t0) : TILE;
        for (int i = tid; i < NBK; i += 1024) lh[i] = 0;
        __syncthreads();
        for (int i = tid; i < lim; i += 1024)
            atomicAdd(&lh[dst[t0 + i] >> BSH], 1);
        __syncthreads();
        for (int b = tid; b < NBK; b += 1024) {
            int c = lh[b];
            lbase[b] = c ? atomicAdd(&gcur[b], c) : 0;
        }
        __syncthreads();
        for (int i = tid; i < NBK; i += 1024) lh[i] = 0;
        __syncthreads();
        for (int i = tid; i < lim; i += 1024) {
            int d = dst[t0 + i];
            int b = d >> BSH;
            int r = atomicAdd(&lh[b], 1);
            pairs[lbase[b] + r] = ((unsigned)(d & (BNODES - 1)) << 23) | (unsigned)src[t0 + i];
        }
        __syncthreads();
    }
    grid.sync();

    // ---- phase 4: per-bucket counting sort -> csr, rowstart, dinv, fused xnh ----
    if (bid >= NBK) return;
    int nodeBase = bid << BSH;
    int st = bbase[bid], en = bbase[bid + 1];
    int m = en - st;
    for (int i = tid; i < BNODES; i += 1024) { cnt[i] = 0; lcur[i] = 0; }
    __syncthreads();
    for (int i = tid; i < m; i += 1024)
        atomicAdd(&cnt[pairs[st + i] >> 23], 1);
    __syncthreads();
    if (tid < BNODES) lex[tid] = cnt[tid];
    __syncthreads();
    for (int off = 1; off < BNODES; off <<= 1) {
        int a = 0;
        if (tid < BNODES && tid >= off) a = lex[tid - off];
        __syncthreads();
        if (tid < BNODES) lex[tid] += a;
        __syncthreads();
    }
    if (tid < BNODES) {
        int ex = lex[tid] - cnt[tid];        // exclusive
        int v = nodeBase + tid;
        float dv = rsqrtf((float)(cnt[tid] + 1));
        dinvl[tid] = dv;
        if (v < N) {
            rowstart[v] = st + ex;
            dinv[v] = dv;
        }
        lex[tid] = ex;
    }
    __syncthreads();
    if (m <= CAP) {
        for (int i = tid; i < m; i += 1024) {
            unsigned p = pairs[st + i];
            int ld = p >> 23;
            int r = atomicAdd(&lcur[ld], 1);
            lsorted[lex[ld] + r] = (int)(p & SRCMASK);
        }
        __syncthreads();
        for (int i = tid; i < m; i += 1024) csr[st + i] = lsorted[i];
    } else {  // overflow fallback: direct global placement
        for (int i = tid; i < m; i += 1024) {
            unsigned p = pairs[st + i];
            int ld = p >> 23;
            int r = atomicAdd(&lcur[ld], 1);
            csr[st + lex[ld] + r] = (int)(p & SRCMASK);
        }
    }
    // fused xn: xnh[v][cp] = half2(x[v][2cp], x[v][2cp+1]) * dinv, 16 cols 0-pad
    for (int i = tid; i < BNODES * 8; i += 1024) {
        int n = i >> 3, cp = i & 7;
        int v = nodeBase + n;
        if (v < N) {
            float dv = dinvl[n];
            int c0 = 2 * cp, c1 = c0 + 1;
            float a = (c0 < FIN) ? x[(size_t)v * FIN + c0] * dv : 0.f;
            float b = (c1 < FIN) ? x[(size_t)v * FIN + c1] * dv : 0.f;
            xnh[(size_t)v * 8 + cp] = __floats2half2_rn(a, b);
        }
    }
}

// ---------- fused layer1: gather-agg fp16 xn (4 slots, dual-unrolled) -> relu(@W1+b1) -> @W2 *dinv -> fp16 y2 ----------
// 512 thr = 32 nodes x (4 slots x 4 col-lanes); lane reads 8B (4 fp16 cols)
__global__ void __launch_bounds__(512)
k_agg1t(const uint2* __restrict__ xnh, const int* __restrict__ rowstart,
        const float* __restrict__ dinv, const int* __restrict__ csr,
        const float* __restrict__ W1, const float* __restrict__ b1,
        const float* __restrict__ W2, __half2* __restrict__ y2h, int N) {
    __shared__ float sW1[FIN * F1];
    __shared__ float sb1[F1];
    __shared__ float sW2[F1 * F2];
    __shared__ float sagg[32][16];
    __shared__ float sh[32][65];          // pad 65: conflict-free column reads
    int tid = threadIdx.x;
    for (int i = tid; i < FIN * F1; i += 512) sW1[i] = W1[i];
    for (int i = tid; i < F1 * F2; i += 512) sW2[i] = W2[i];
    if (tid < F1) sb1[tid] = b1[tid];
    int ln = tid >> 4;           // local node 0..31
    int slot = (tid >> 2) & 3;   // edge slot 0..3
    int l = tid & 3;             // col-lane: cols 4l..4l+3
    int base = blockIdx.x * 32;
    int v = base + ln;
    float4 acc = make_float4(0.f, 0.f, 0.f, 0.f);
    if (v < N) {
        int st = rowstart[v];
        int en = rowstart[v + 1];
        int e = st + slot;
        while (e + 4 < en) {
            int s0 = csr[e];
            int s1 = csr[e + 4];
            uint2 u0 = xnh[(size_t)s0 * 4 + l];
            uint2 u1 = xnh[(size_t)s1 * 4 + l];
            float2 a0 = __half22float2(*reinterpret_cast<__half2*>(&u0.x));
            float2 a1 = __half22float2(*reinterpret_cast<__half2*>(&u0.y));
            float2 b0 = __half22float2(*reinterpret_cast<__half2*>(&u1.x));
            float2 b1_ = __half22float2(*reinterpret_cast<__half2*>(&u1.y));
            acc.x += a0.x + b0.x; acc.y += a0.y + b0.y;
            acc.z += a1.x + b1_.x; acc.w += a1.y + b1_.y;
            e += 8;
        }
        if (e < en) {
            int s0 = csr[e];
            uint2 u0 = xnh[(size_t)s0 * 4 + l];
            float2 a0 = __half22float2(*reinterpret_cast<__half2*>(&u0.x));
            float2 a1 = __half22float2(*reinterpret_cast<__half2*>(&u0.y));
            acc.x += a0.x; acc.y += a0.y; acc.z += a1.x; acc.w += a1.y;
        }
    }
    acc.x += __shfl_xor(acc.x, 4); acc.y += __shfl_xor(acc.y, 4);
    acc.z += __shfl_xor(acc.z, 4); acc.w += __shfl_xor(acc.w, 4);
    acc.x += __shfl_xor(acc.x, 8); acc.y += __shfl_xor(acc.y, 8);
    acc.z += __shfl_xor(acc.z, 8); acc.w += __shfl_xor(acc.w, 8);
    if (v < N && slot == 0) {
        uint2 u = xnh[(size_t)v * 4 + l];   // self (has one dinv)
        float2 f0 = __half22float2(*reinterpret_cast<__half2*>(&u.x));
        float2 f1 = __half22float2(*reinterpret_cast<__half2*>(&u.y));
        float dv = dinv[v];
        sagg[ln][l * 4 + 0] = (f0.x + acc.x) * dv;
        sagg[ln][l * 4 + 1] = (f0.y + acc.y) * dv;
        sagg[ln][l * 4 + 2] = (f1.x + acc.z) * dv;
        sagg[ln][l * 4 + 3] = (f1.y + acc.w) * dv;
    }
    __syncthreads();
    {
        int col = tid & 63;
        int sub = tid >> 6;      // 0..7
        for (int nn = sub; nn < 32; nn += 8) {
            if (base + nn >= N) break;
            float acc1 = sb1[col];
#pragma unroll
            for (int k = 0; k < FIN; ++k) acc1 += sagg[nn][k] * sW1[k * F1 + col];
            sh[nn][col] = fmaxf(acc1, 0.f);
        }
    }
    __syncthreads();
    {
        int nn = tid >> 4;       // node 0..31
        int cp = tid & 15;       // col pair: cols 2cp, 2cp+1
        int v2 = base + nn;
        if (v2 < N) {
            float a0 = 0.f, a1 = 0.f;
#pragma unroll
            for (int k = 0; k < F1; ++k) {
                float hv = sh[nn][k];
                a0 += hv * sW2[k * F2 + 2 * cp];
                a1 += hv * sW2[k * F2 + 2 * cp + 1];
            }
            float dv = dinv[v2];
            y2h[(size_t)v2 * 16 + cp] = __floats2half2_rn(a0 * dv, a1 * dv);
        }
    }
}

// ---------- layer2 aggregate fp16 (4 slots, dual-unrolled): out2 = dinv*(y2[self]+sum y2[src]) + b2 ----------
// 512 thr = 16 nodes x (4 slots x 8 lanes)
__global__ void __launch_bounds__(512)
k_agg2(const uint2* __restrict__ y2h, const int* __restrict__ rowstart,
       const float* __restrict__ dinv, const int* __restrict__ csr,
       const float* __restrict__ b2, float4* __restrict__ out2, int N) {
    int tid = threadIdx.x;
    int ln = tid >> 5;           // local node 0..15
    int slot = (tid >> 3) & 3;   // edge slot 0..3
    int l = tid & 7;             // lane: cols 4l..4l+3
    int v = blockIdx.x * 16 + ln;
    if (v >= N) return;
    int st = rowstart[v];
    int en = rowstart[v + 1];
    float4 acc = make_float4(0.f, 0.f, 0.f, 0.f);
    int e = st + slot;
    while (e + 4 < en) {
        int s0 = csr[e];
        int s1 = csr[e + 4];
        uint2 u0 = y2h[(size_t)s0 * 8 + l];
        uint2 u1 = y2h[(size_t)s1 * 8 + l];
        float2 a0 = __half22float2(*reinterpret_cast<__half2*>(&u0.x));
        float2 a1 = __half22float2(*reinterpret_cast<__half2*>(&u0.y));
        float2 b0 = __half22float2(*reinterpret_cast<__half2*>(&u1.x));
        float2 b1_ = __half22float2(*reinterpret_cast<__half2*>(&u1.y));
        acc.x += a0.x + b0.x; acc.y += a0.y + b0.y;
        acc.z += a1.x + b1_.x; acc.w += a1.y + b1_.y;
        e += 8;
    }
    if (e < en) {
        int s0 = csr[e];
        uint2 u0 = y2h[(size_t)s0 * 8 + l];
        float2 a0 = __half22float2(*reinterpret_cast<__half2*>(&u0.x));
        float2 a1 = __half22float2(*reinterpret_cast<__half2*>(&u0.y));
        acc.x += a0.x; acc.y += a0.y; acc.z += a1.x; acc.w += a1.y;
    }
    acc.x += __shfl_xor(acc.x, 8);  acc.y += __shfl_xor(acc.y, 8);
    acc.z += __shfl_xor(acc.z, 8);  acc.w += __shfl_xor(acc.w, 8);
    acc.x += __shfl_xor(acc.x, 16); acc.y += __shfl_xor(acc.y, 16);
    acc.z += __shfl_xor(acc.z, 16); acc.w += __shfl_xor(acc.w, 16);
    if (slot == 0) {
        uint2 u = y2h[(size_t)v * 8 + l];
        float2 f0 = __half22float2(*reinterpret_cast<__half2*>(&u.x));
        float2 f1 = __half22float2(*reinterpret_cast<__half2*>(&u.y));
        float dv = dinv[v];
        float4 bb = ((const float4*)b2)[l];
        float4 o;
        o.x = (f0.x + acc.x) * dv + bb.x;
        o.y = (f0.y + acc.y) * dv + bb.y;
        o.z = (f1.x + acc.z) * dv + bb.z;
        o.w = (f1.y + acc.w) * dv + bb.w;
        out2[(size_t)v * 8 + l] = o;
    }
}

// ---------- fused mean-pool + MLP (graph bounds via binary search) ----------
__global__ void k_poolmlp(const float* __restrict__ out2, const int* __restrict__ batch,
                          const float* __restrict__ fc1w, const float* __restrict__ fc1b,
                          const float* __restrict__ fc2w, const float* __restrict__ fc2b,
                          float* __restrict__ out, int N, int G) {
    __shared__ float sW1[F2 * F2];
    __shared__ float sW2[F2 * F2];
    __shared__ float part[8][F2];
    __shared__ float gvec[F2];
    __shared__ float h1[F2];
    __shared__ int bounds[2];
    int tid = threadIdx.x;
    for (int i = tid; i < F2 * F2; i += 256) {
        sW1[i] = fc1w[i];
        sW2[i] = fc2w[i];
    }
    int g = blockIdx.x;
    if (tid < 2) {
        int target = g + tid;
        int lo = 0, hi = N;
        while (lo < hi) {
            int mid = (lo + hi) >> 1;
            if (batch[mid] < target) lo = mid + 1; else hi = mid;
        }
        bounds[tid] = lo;
    }
    __syncthreads();
    int st = bounds[0], en = bounds[1];
    int r = tid >> 5, c = tid & 31;
    float acc = 0.f;
    for (int v = st + r; v < en; v += 8) acc += out2[(size_t)v * F2 + c];
    part[r][c] = acc;
    __syncthreads();
    if (tid < F2) {
        float s = 0.f;
#pragma unroll
        for (int i = 0; i < 8; ++i) s += part[i][tid];
        float cnt = (float)(en - st);
        gvec[tid] = s / fmaxf(cnt, 1.0f);
    }
    __syncthreads();
    if (tid < F2) {
        float a = fc1b[tid];
#pragma unroll
        for (int k = 0; k < F2; ++k) a += gvec[k] * sW1[k * F2 + tid];
        h1[tid] = fmaxf(a, 0.f);
    }
    __syncthreads();
    if (tid < F2) {
        float a = fc2b[tid];
#pragma unroll
        for (int k = 0; k < F2; ++k) a += h1[k] * sW2[k * F2 + tid];
        out[(size_t)g * F2 + tid] = a;
    }
}

extern "C" void kernel_launch(void* const* d_in, const int* in_sizes, int n_in,
                              void* d_out, int out_size, void* d_ws, size_t ws_size,
                              hipStream_t stream) {
    const float* x    = (const float*)d_in[0];
    const int*   ei   = (const int*)d_in[1];
    const int*   batch= (const int*)d_in[2];
    const float* W1   = (const float*)d_in[3];
    const float* b1   = (const float*)d_in[4];
    const float* W2   = (const float*)d_in[5];
    const float* b2   = (const float*)d_in[6];
    const float* fc1w = (const float*)d_in[7];
    const float* fc1b = (const float*)d_in[8];
    const float* fc2w = (const float*)d_in[9];
    const float* fc2b = (const float*)d_in[10];
    float* out = (float*)d_out;

    const int N = in_sizes[0] / FIN;       // 100000
    const int E = in_sizes[1] / 2;         // 1250000
    const int G = out_size / F2;           // 512
    const int* src = ei;
    const int* dst = ei + E;
    const int NBK = (N + BNODES - 1) >> BSH;   // 196

    // ---- workspace layout (4-byte units) ----
    int* wsi = (int*)d_ws;
    int* bpart    = wsi;                   // PB * BPAD
    int* bbase    = bpart + PB * BPAD;     // NBK+1
    int* gcur     = bbase + NBK + 1;       // NBK
    int* rowstart = gcur + NBK;            // N+1
    int* csr      = rowstart + (N + 1);    // E
    unsigned* pairs = (unsigned*)(csr + E);// E (packed)
    size_t off = (size_t)(PB * BPAD + 2 * NBK + 1 + N + 1) + 2 * (size_t)E;
    off = (off + 3) & ~(size_t)3;          // 16B align
    float* dinv = (float*)(wsi + off);               // N
    size_t nal = (size_t)((N + 3) & ~3);
    __half2* xnh = (__half2*)(dinv + nal);           // N*8 words (16 fp16/node)
    __half2* y2h = (__half2*)((int*)xnh + (size_t)N * 8);   // N*16 words (32 fp16/node)
    float* out2 = (float*)((int*)y2h + (size_t)N * 16);     // N*32

    // cooperative preprocessing (hist + scan + scatter + sort + xn)
    {
        const int* srcp = src; const int* dstp = dst; const float* xp = x;
        int Nv = N, Ev = E, NBKv = NBK;
        int* bpartp = bpart; int* bbasep = bbase; int* gcurp = gcur;
        int* rowstartp = rowstart; float* dinvp = dinv; int* csrp = csr;
        unsigned* pairsp = pairs; __half2* xnhp = xnh;
        void* args[] = { &srcp, &dstp, &xp, &bpartp, &bbasep, &gcurp,
                         &rowstartp, &dinvp, &csrp, &pairsp, &xnhp,
                         &Nv, &Ev, &NBKv };
        hipLaunchCooperativeKernel((const void*)k_prep, dim3(PB), dim3(1024),
                                   args, 0, stream);
    }
    hipLaunchKernelGGL(k_agg1t, dim3((N + 31) / 32), dim3(512), 0, stream,
                       (const uint2*)xnh, rowstart, dinv, csr, W1, b1, W2, y2h, N);
    hipLaunchKernelGGL(k_agg2, dim3((N + 15) / 16), dim3(512), 0, stream,
                       (const uint2*)y2h, rowstart, dinv, csr, b2, (float4*)out2, N);
    hipLaunchKernelGGL(k_poolmlp, dim3(G), dim3(256), 0, stream,
                       out2, batch, fc1w, fc1b, fc2w, fc2b, out, N, G);
}

// Round 14
// 137.194 us; speedup vs baseline: 1.8021x; 1.8021x over previous
//
#include <hip/hip_runtime.h>
#include <hip/hip_fp16.h>

#define F1 64
#define F2 32
#define FIN 13
#define BSH 9                 // bucket = dst >> 9  (512 nodes/bucket)
#define BNODES 512
#define TILE 4096             // edges per scatter block
#define SCT 256               // scatter threads
#define CAP 8192              // LDS sort capacity (bucket mean 6400, sd ~80)
#define SRCMASK 0x7FFFFF      // 23-bit src (N < 8.4M)
#define HB 256                // histogram blocks
#define BPAD 208              // bpart row stride (>= NBK)
#define ECAP1 1536            // agg1 LDS csr slice (32 nodes, mean 400)
#define ECAP2 1024            // agg2 LDS csr slice (16 nodes, mean 200)

// ---------- bucket histogram: per-block partials, no global atomics, no pre-zero ----------
__global__ void __launch_bounds__(256)
k_bhist(const int* __restrict__ dst, int* __restrict__ bpart, int E, int NBK) {
    __shared__ int lh[256];
    int tid = threadIdx.x;
    for (int i = tid; i < NBK; i += 256) lh[i] = 0;
    __syncthreads();
    int stride = gridDim.x * 256;
    for (int e = blockIdx.x * 256 + tid; e < E; e += stride)
        atomicAdd(&lh[dst[e] >> BSH], 1);
    __syncthreads();
    for (int i = tid; i < NBK; i += 256)
        bpart[blockIdx.x * BPAD + i] = lh[i];
}

// ---------- reduce partials -> scan -> bbase (exclusive), init gcursor, sentinel ----------
__global__ void k_bscan(const int* __restrict__ bpart, int* __restrict__ bbase,
                        int* __restrict__ gcur, int* __restrict__ rowstart,
                        int NBK, int N, int E) {
    __shared__ int s[256];
    int t = threadIdx.x;
    int v = 0;
    if (t < NBK) {
#pragma unroll 8
        for (int k = 0; k < HB; ++k) v += bpart[k * BPAD + t];
    }
    s[t] = v;
    __syncthreads();
    for (int off = 1; off < 256; off <<= 1) {
        int a = (t >= off) ? s[t - off] : 0;
        __syncthreads();
        s[t] += a;
        __syncthreads();
    }
    if (t < NBK) {
        int excl = s[t] - v;
        bbase[t] = excl;
        gcur[t] = excl;
        if (t == NBK - 1) bbase[NBK] = s[t];
    }
    if (t == 0) rowstart[N] = E;
}

// ---------- partition edges into bucket-contiguous packed (ldst<<23|src) ----------
__global__ void __launch_bounds__(SCT)
k_bscatter(const int* __restrict__ src, const int* __restrict__ dst,
           int* __restrict__ gcur, unsigned* __restrict__ pairs,
           int E, int NBK) {
    __shared__ int lh[256];
    __shared__ int lbase[256];
    int tid = threadIdx.x;
    long t0 = (long)blockIdx.x * TILE;
    int lim = (int)min((long)TILE, (long)E - t0);
    for (int i = tid; i < NBK; i += SCT) lh[i] = 0;
    __syncthreads();
    for (int i = tid; i < lim; i += SCT)
        atomicAdd(&lh[dst[t0 + i] >> BSH], 1);
    __syncthreads();
    for (int b = tid; b < NBK; b += SCT) {
        int c = lh[b];
        lbase[b] = c ? atomicAdd(&gcur[b], c) : 0;
    }
    __syncthreads();
    for (int i = tid; i < NBK; i += SCT) lh[i] = 0;
    __syncthreads();
    for (int i = tid; i < lim; i += SCT) {
        int d = dst[t0 + i];
        int b = d >> BSH;
        int r = atomicAdd(&lh[b], 1);
        pairs[lbase[b] + r] = ((unsigned)(d & (BNODES - 1)) << 23) | (unsigned)src[t0 + i];
    }
}

// ---------- per-bucket counting sort -> csr (coalesced), rowstart, dinv, fused xn ----------
__global__ void __launch_bounds__(1024)
k_bsort(const unsigned* __restrict__ pairs, const int* __restrict__ bbase,
        const float* __restrict__ x, int* __restrict__ rowstart,
        float* __restrict__ dinv, int* __restrict__ csr,
        __half2* __restrict__ xnh, int N) {
    __shared__ int cnt[BNODES];
    __shared__ int lex[BNODES];
    __shared__ int lcur[BNODES];
    __shared__ float dinvl[BNODES];
    __shared__ int lsorted[CAP];
    int tid = threadIdx.x;
    int bk = blockIdx.x;
    int nodeBase = bk << BSH;
    int st = bbase[bk], en = bbase[bk + 1];
    int m = en - st;
    for (int i = tid; i < BNODES; i += 1024) { cnt[i] = 0; lcur[i] = 0; }
    __syncthreads();
    for (int i = tid; i < m; i += 1024)
        atomicAdd(&cnt[pairs[st + i] >> 23], 1);
    __syncthreads();
    if (tid < BNODES) lex[tid] = cnt[tid];
    __syncthreads();
    for (int off = 1; off < BNODES; off <<= 1) {
        int a = 0;
        if (tid < BNODES && tid >= off) a = lex[tid - off];
        __syncthreads();
        if (tid < BNODES) lex[tid] += a;
        __syncthreads();
    }
    if (tid < BNODES) {
        int ex = lex[tid] - cnt[tid];        // exclusive
        int v = nodeBase + tid;
        float dv = rsqrtf((float)(cnt[tid] + 1));
        dinvl[tid] = dv;
        if (v < N) {
            rowstart[v] = st + ex;
            dinv[v] = dv;
        }
        lex[tid] = ex;
    }
    __syncthreads();
    if (m <= CAP) {
        for (int i = tid; i < m; i += 1024) {
            unsigned p = pairs[st + i];
            int ld = p >> 23;
            int r = atomicAdd(&lcur[ld], 1);
            lsorted[lex[ld] + r] = (int)(p & SRCMASK);
        }
        __syncthreads();
        for (int i = tid; i < m; i += 1024) csr[st + i] = lsorted[i];
    } else {
        for (int i = tid; i < m; i += 1024) {
            unsigned p = pairs[st + i];
            int ld = p >> 23;
            int r = atomicAdd(&lcur[ld], 1);
            csr[st + lex[ld] + r] = (int)(p & SRCMASK);
        }
    }
    // fused xn: xnh[v][cp] = half2(x[v][2cp], x[v][2cp+1]) * dinv, 16 cols 0-pad
    for (int i = tid; i < BNODES * 8; i += 1024) {
        int n = i >> 3, cp = i & 7;
        int v = nodeBase + n;
        if (v < N) {
            float dv = dinvl[n];
            int c0 = 2 * cp, c1 = c0 + 1;
            float a = (c0 < FIN) ? x[(size_t)v * FIN + c0] * dv : 0.f;
            float b = (c1 < FIN) ? x[(size_t)v * FIN + c1] * dv : 0.f;
            xnh[(size_t)v * 8 + cp] = __floats2half2_rn(a, b);
        }
    }
}

// ---------- fused layer1: LDS-staged csr slice + gather-agg fp16 xn -> relu(@W1+b1) -> @W2 *dinv -> fp16 y2 ----------
// 512 thr = 32 nodes x (4 slots x 4 col-lanes); lane reads 8B (4 fp16 cols)
__global__ void __launch_bounds__(512)
k_agg1t(const uint2* __restrict__ xnh, const int* __restrict__ rowstart,
        const float* __restrict__ dinv, const int* __restrict__ csr,
        const float* __restrict__ W1, const float* __restrict__ b1,
        const float* __restrict__ W2, __half2* __restrict__ y2h, int N) {
    __shared__ float sW1[FIN * F1];
    __shared__ float sb1[F1];
    __shared__ float sW2[F1 * F2];
    __shared__ float sagg[32][16];
    __shared__ float sh[32][65];          // pad 65: conflict-free column reads
    __shared__ int lcsr[ECAP1];
    int tid = threadIdx.x;
    for (int i = tid; i < FIN * F1; i += 512) sW1[i] = W1[i];
    for (int i = tid; i < F1 * F2; i += 512) sW2[i] = W2[i];
    if (tid < F1) sb1[tid] = b1[tid];
    int base = blockIdx.x * 32;
    int nEnd = (base + 32 < N) ? base + 32 : N;
    int st0 = rowstart[base];
    int en0 = rowstart[nEnd];
    int mblk = en0 - st0;
    bool inlds = (mblk <= ECAP1);
    if (inlds) {
        for (int i = tid; i < mblk; i += 512) lcsr[i] = csr[st0 + i];
    }
    __syncthreads();
    int ln = tid >> 4;           // local node 0..31
    int slot = (tid >> 2) & 3;   // edge slot 0..3
    int l = tid & 3;             // col-lane: cols 4l..4l+3
    int v = base + ln;
    float4 acc = make_float4(0.f, 0.f, 0.f, 0.f);
    if (v < N) {
        int st = rowstart[v];
        int en = rowstart[v + 1];
        if (inlds) {
            int e = st - st0 + slot;
            int enl = en - st0;
            while (e + 4 < enl) {
                int s0 = lcsr[e];
                int s1 = lcsr[e + 4];
                uint2 u0 = xnh[(size_t)s0 * 4 + l];
                uint2 u1 = xnh[(size_t)s1 * 4 + l];
                float2 a0 = __half22float2(*reinterpret_cast<__half2*>(&u0.x));
                float2 a1 = __half22float2(*reinterpret_cast<__half2*>(&u0.y));
                float2 b0 = __half22float2(*reinterpret_cast<__half2*>(&u1.x));
                float2 b1_ = __half22float2(*reinterpret_cast<__half2*>(&u1.y));
                acc.x += a0.x + b0.x; acc.y += a0.y + b0.y;
                acc.z += a1.x + b1_.x; acc.w += a1.y + b1_.y;
                e += 8;
            }
            if (e < enl) {
                int s0 = lcsr[e];
                uint2 u0 = xnh[(size_t)s0 * 4 + l];
                float2 a0 = __half22float2(*reinterpret_cast<__half2*>(&u0.x));
                float2 a1 = __half22float2(*reinterpret_cast<__half2*>(&u0.y));
                acc.x += a0.x; acc.y += a0.y; acc.z += a1.x; acc.w += a1.y;
            }
        } else {
            int e = st + slot;
            while (e + 4 < en) {
                int s0 = csr[e];
                int s1 = csr[e + 4];
                uint2 u0 = xnh[(size_t)s0 * 4 + l];
                uint2 u1 = xnh[(size_t)s1 * 4 + l];
                float2 a0 = __half22float2(*reinterpret_cast<__half2*>(&u0.x));
                float2 a1 = __half22float2(*reinterpret_cast<__half2*>(&u0.y));
                float2 b0 = __half22float2(*reinterpret_cast<__half2*>(&u1.x));
                float2 b1_ = __half22float2(*reinterpret_cast<__half2*>(&u1.y));
                acc.x += a0.x + b0.x; acc.y += a0.y + b0.y;
                acc.z += a1.x + b1_.x; acc.w += a1.y + b1_.y;
                e += 8;
            }
            if (e < en) {
                int s0 = csr[e];
                uint2 u0 = xnh[(size_t)s0 * 4 + l];
                float2 a0 = __half22float2(*reinterpret_cast<__half2*>(&u0.x));
                float2 a1 = __half22float2(*reinterpret_cast<__half2*>(&u0.y));
                acc.x += a0.x; acc.y += a0.y; acc.z += a1.x; acc.w += a1.y;
            }
        }
    }
    acc.x += __shfl_xor(acc.x, 4); acc.y += __shfl_xor(acc.y, 4);
    acc.z += __shfl_xor(acc.z, 4); acc.w += __shfl_xor(acc.w, 4);
    acc.x += __shfl_xor(acc.x, 8); acc.y += __shfl_xor(acc.y, 8);
    acc.z += __shfl_xor(acc.z, 8); acc.w += __shfl_xor(acc.w, 8);
    if (v < N && slot == 0) {
        uint2 u = xnh[(size_t)v * 4 + l];   // self (has one dinv)
        float2 f0 = __half22float2(*reinterpret_cast<__half2*>(&u.x));
        float2 f1 = __half22float2(*reinterpret_cast<__half2*>(&u.y));
        float dv = dinv[v];
        sagg[ln][l * 4 + 0] = (f0.x + acc.x) * dv;
        sagg[ln][l * 4 + 1] = (f0.y + acc.y) * dv;
        sagg[ln][l * 4 + 2] = (f1.x + acc.z) * dv;
        sagg[ln][l * 4 + 3] = (f1.y + acc.w) * dv;
    }
    __syncthreads();
    {
        int col = tid & 63;
        int sub = tid >> 6;      // 0..7
        for (int nn = sub; nn < 32; nn += 8) {
            if (base + nn >= N) break;
            float acc1 = sb1[col];
#pragma unroll
            for (int k = 0; k < FIN; ++k) acc1 += sagg[nn][k] * sW1[k * F1 + col];
            sh[nn][col] = fmaxf(acc1, 0.f);
        }
    }
    __syncthreads();
    {
        int nn = tid >> 4;       // node 0..31
        int cp = tid & 15;       // col pair: cols 2cp, 2cp+1
        int v2 = base + nn;
        if (v2 < N) {
            float a0 = 0.f, a1 = 0.f;
#pragma unroll
            for (int k = 0; k < F1; ++k) {
                float hv = sh[nn][k];
                a0 += hv * sW2[k * F2 + 2 * cp];
                a1 += hv * sW2[k * F2 + 2 * cp + 1];
            }
            float dv = dinv[v2];
            y2h[(size_t)v2 * 16 + cp] = __floats2half2_rn(a0 * dv, a1 * dv);
        }
    }
}

// ---------- layer2 aggregate fp16 with LDS-staged csr slice: out2 = dinv*(y2[self]+sum y2[src]) + b2 ----------
// 512 thr = 16 nodes x (4 slots x 8 lanes)
__global__ void __launch_bounds__(512)
k_agg2(const uint2* __restrict__ y2h, const int* __restrict__ rowstart,
       const float* __restrict__ dinv, const int* __restrict__ csr,
       const float* __restrict__ b2, float4* __restrict__ out2, int N) {
    __shared__ int lcsr[ECAP2];
    int tid = threadIdx.x;
    int base = blockIdx.x * 16;
    int nEnd = (base + 16 < N) ? base + 16 : N;
    int st0 = rowstart[base];
    int en0 = rowstart[nEnd];
    int mblk = en0 - st0;
    bool inlds = (mblk <= ECAP2);
    if (inlds) {
        for (int i = tid; i < mblk; i += 512) lcsr[i] = csr[st0 + i];
    }
    __syncthreads();
    int ln = tid >> 5;           // local node 0..15
    int slot = (tid >> 3) & 3;   // edge slot 0..3
    int l = tid & 7;             // lane: cols 4l..4l+3
    int v = base + ln;
    if (v >= N) return;
    int st = rowstart[v];
    int en = rowstart[v + 1];
    float4 acc = make_float4(0.f, 0.f, 0.f, 0.f);
    if (inlds) {
        int e = st - st0 + slot;
        int enl = en - st0;
        while (e + 4 < enl) {
            int s0 = lcsr[e];
            int s1 = lcsr[e + 4];
            uint2 u0 = y2h[(size_t)s0 * 8 + l];
            uint2 u1 = y2h[(size_t)s1 * 8 + l];
            float2 a0 = __half22float2(*reinterpret_cast<__half2*>(&u0.x));
            float2 a1 = __half22float2(*reinterpret_cast<__half2*>(&u0.y));
            float2 b0 = __half22float2(*reinterpret_cast<__half2*>(&u1.x));
            float2 b1_ = __half22float2(*reinterpret_cast<__half2*>(&u1.y));
            acc.x += a0.x + b0.x; acc.y += a0.y + b0.y;
            acc.z += a1.x + b1_.x; acc.w += a1.y + b1_.y;
            e += 8;
        }
        if (e < enl) {
            int s0 = lcsr[e];
            uint2 u0 = y2h[(size_t)s0 * 8 + l];
            float2 a0 = __half22float2(*reinterpret_cast<__half2*>(&u0.x));
            float2 a1 = __half22float2(*reinterpret_cast<__half2*>(&u0.y));
            acc.x += a0.x; acc.y += a0.y; acc.z += a1.x; acc.w += a1.y;
        }
    } else {
        int e = st + slot;
        while (e + 4 < en) {
            int s0 = csr[e];
            int s1 = csr[e + 4];
            uint2 u0 = y2h[(size_t)s0 * 8 + l];
            uint2 u1 = y2h[(size_t)s1 * 8 + l];
            float2 a0 = __half22float2(*reinterpret_cast<__half2*>(&u0.x));
            float2 a1 = __half22float2(*reinterpret_cast<__half2*>(&u0.y));
            float2 b0 = __half22float2(*reinterpret_cast<__half2*>(&u1.x));
            float2 b1_ = __half22float2(*reinterpret_cast<__half2*>(&u1.y));
            acc.x += a0.x + b0.x; acc.y += a0.y + b0.y;
            acc.z += a1.x + b1_.x; acc.w += a1.y + b1_.y;
            e += 8;
        }
        if (e < en) {
            int s0 = csr[e];
            uint2 u0 = y2h[(size_t)s0 * 8 + l];
            float2 a0 = __half22float2(*reinterpret_cast<__half2*>(&u0.x));
            float2 a1 = __half22float2(*reinterpret_cast<__half2*>(&u0.y));
            acc.x += a0.x; acc.y += a0.y; acc.z += a1.x; acc.w += a1.y;
        }
    }
    acc.x += __shfl_xor(acc.x, 8);  acc.y += __shfl_xor(acc.y, 8);
    acc.z += __shfl_xor(acc.z, 8);  acc.w += __shfl_xor(acc.w, 8);
    acc.x += __shfl_xor(acc.x, 16); acc.y += __shfl_xor(acc.y, 16);
    acc.z += __shfl_xor(acc.z, 16); acc.w += __shfl_xor(acc.w, 16);
    if (slot == 0) {
        uint2 u = y2h[(size_t)v * 8 + l];
        float2 f0 = __half22float2(*reinterpret_cast<__half2*>(&u.x));
        float2 f1 = __half22float2(*reinterpret_cast<__half2*>(&u.y));
        float dv = dinv[v];
        float4 bb = ((const float4*)b2)[l];
        float4 o;
        o.x = (f0.x + acc.x) * dv + bb.x;
        o.y = (f0.y + acc.y) * dv + bb.y;
        o.z = (f1.x + acc.z) * dv + bb.z;
        o.w = (f1.y + acc.w) * dv + bb.w;
        out2[(size_t)v * 8 + l] = o;
    }
}

// ---------- fused mean-pool + MLP (graph bounds via binary search) ----------
__global__ void k_poolmlp(const float* __restrict__ out2, const int* __restrict__ batch,
                          const float* __restrict__ fc1w, const float* __restrict__ fc1b,
                          const float* __restrict__ fc2w, const float* __restrict__ fc2b,
                          float* __restrict__ out, int N, int G) {
    __shared__ float sW1[F2 * F2];
    __shared__ float sW2[F2 * F2];
    __shared__ float part[8][F2];
    __shared__ float gvec[F2];
    __shared__ float h1[F2];
    __shared__ int bounds[2];
    int tid = threadIdx.x;
    for (int i = tid; i < F2 * F2; i += 256) {
        sW1[i] = fc1w[i];
        sW2[i] = fc2w[i];
    }
    int g = blockIdx.x;
    if (tid < 2) {
        int target = g + tid;
        int lo = 0, hi = N;
        while (lo < hi) {
            int mid = (lo + hi) >> 1;
            if (batch[mid] < target) lo = mid + 1; else hi = mid;
        }
        bounds[tid] = lo;
    }
    __syncthreads();
    int st = bounds[0], en = bounds[1];
    int r = tid >> 5, c = tid & 31;
    float acc = 0.f;
    for (int v = st + r; v < en; v += 8) acc += out2[(size_t)v * F2 + c];
    part[r][c] = acc;
    __syncthreads();
    if (tid < F2) {
        float s = 0.f;
#pragma unroll
        for (int i = 0; i < 8; ++i) s += part[i][tid];
        float cnt = (float)(en - st);
        gvec[tid] = s / fmaxf(cnt, 1.0f);
    }
    __syncthreads();
    if (tid < F2) {
        float a = fc1b[tid];
#pragma unroll
        for (int k = 0; k < F2; ++k) a += gvec[k] * sW1[k * F2 + tid];
        h1[tid] = fmaxf(a, 0.f);
    }
    __syncthreads();
    if (tid < F2) {
        float a = fc2b[tid];
#pragma unroll
        for (int k = 0; k < F2; ++k) a += h1[k] * sW2[k * F2 + tid];
        out[(size_t)g * F2 + tid] = a;
    }
}

extern "C" void kernel_launch(void* const* d_in, const int* in_sizes, int n_in,
                              void* d_out, int out_size, void* d_ws, size_t ws_size,
                              hipStream_t stream) {
    const float* x    = (const float*)d_in[0];
    const int*   ei   = (const int*)d_in[1];
    const int*   batch= (const int*)d_in[2];
    const float* W1   = (const float*)d_in[3];
    const float* b1   = (const float*)d_in[4];
    const float* W2   = (const float*)d_in[5];
    const float* b2   = (const float*)d_in[6];
    const float* fc1w = (const float*)d_in[7];
    const float* fc1b = (const float*)d_in[8];
    const float* fc2w = (const float*)d_in[9];
    const float* fc2b = (const float*)d_in[10];
    float* out = (float*)d_out;

    const int N = in_sizes[0] / FIN;       // 100000
    const int E = in_sizes[1] / 2;         // 1250000
    const int G = out_size / F2;           // 512
    const int* src = ei;
    const int* dst = ei + E;
    const int NBK = (N + BNODES - 1) >> BSH;   // 196

    // ---- workspace layout (4-byte units) ----
    int* wsi = (int*)d_ws;
    int* bpart    = wsi;                   // HB * BPAD
    int* bbase    = bpart + HB * BPAD;     // NBK+1
    int* gcur     = bbase + NBK + 1;       // NBK
    int* rowstart = gcur + NBK;            // N+1
    int* csr      = rowstart + (N + 1);    // E
    unsigned* pairs = (unsigned*)(csr + E);// E (packed)
    size_t off = (size_t)(HB * BPAD + 2 * NBK + 1 + N + 1) + 2 * (size_t)E;
    off = (off + 3) & ~(size_t)3;          // 16B align
    float* dinv = (float*)(wsi + off);               // N
    size_t nal = (size_t)((N + 3) & ~3);
    __half2* xnh = (__half2*)(dinv + nal);           // N*8 words (16 fp16/node)
    __half2* y2h = (__half2*)((int*)xnh + (size_t)N * 8);   // N*16 words (32 fp16/node)
    float* out2 = (float*)((int*)y2h + (size_t)N * 16);     // N*32

    const int B = 256;

    hipLaunchKernelGGL(k_bhist, dim3(HB), dim3(B), 0, stream, dst, bpart, E, NBK);
    hipLaunchKernelGGL(k_bscan, dim3(1), dim3(B), 0, stream,
                       bpart, bbase, gcur, rowstart, NBK, N, E);
    hipLaunchKernelGGL(k_bscatter, dim3((E + TILE - 1) / TILE), dim3(SCT), 0, stream,
                       src, dst, gcur, pairs, E, NBK);
    hipLaunchKernelGGL(k_bsort, dim3(NBK), dim3(1024), 0, stream,
                       pairs, bbase, x, rowstart, dinv, csr, xnh, N);
    hipLaunchKernelGGL(k_agg1t, dim3((N + 31) / 32), dim3(512), 0, stream,
                       (const uint2*)xnh, rowstart, dinv, csr, W1, b1, W2, y2h, N);
    hipLaunchKernelGGL(k_agg2, dim3((N + 15) / 16), dim3(512), 0, stream,
                       (const uint2*)y2h, rowstart, dinv, csr, b2, (float4*)out2, N);
    hipLaunchKernelGGL(k_poolmlp, dim3(G), dim3(B), 0, stream,
                       out2, batch, fc1w, fc1b, fc2w, fc2b, out, N, G);
}